// Round 5
// baseline (379.493 us; speedup 1.0000x reference)
//
#include <hip/hip_runtime.h>
#include <hip/hip_bf16.h>
#include <cstdint>
#include <cstddef>

#define B_ROWS 16384
#define D_DIM  256
#define TEMP_INV 14.285714285714286f   // 1/0.07

#define BM 128
#define BN 128

using frag_ab = __attribute__((ext_vector_type(8))) short;   // 8 bf16
using frag_cd = __attribute__((ext_vector_type(4))) float;   // 4 fp32

__device__ __forceinline__ void gld_lds16(const void* g, void* l) {
    __builtin_amdgcn_global_load_lds(
        (const __attribute__((address_space(1))) void*)g,
        (__attribute__((address_space(3))) void*)l,
        16, 0, 0);
}

// Kernel 1: L2-normalize q,d rows -> bf16; diag[i] = cos(q_i,d_i)/T in fp32.
// Also zero-initializes row_sums/col_sums/out (replaces memset dispatches).
__global__ __launch_bounds__(256) void norm_diag_kernel(
    const float* __restrict__ q, const float* __restrict__ d,
    __hip_bfloat16* __restrict__ qn, __hip_bfloat16* __restrict__ dn,
    float* __restrict__ diag,
    float* __restrict__ row_sums, float* __restrict__ col_sums,
    float* __restrict__ out) {
    const int b = blockIdx.x;
    if (b < 64)            row_sums[b * 256 + threadIdx.x] = 0.0f;
    else if (b < 128)      col_sums[(b - 64) * 256 + threadIdx.x] = 0.0f;
    else if (b == 128 && threadIdx.x == 0) out[0] = 0.0f;

    const int row  = b * 4 + (threadIdx.x >> 6);
    const int lane = threadIdx.x & 63;

    const float4 qv = ((const float4*)(q + (size_t)row * D_DIM))[lane];
    const float4 dv = ((const float4*)(d + (size_t)row * D_DIM))[lane];

    float qss = qv.x*qv.x + qv.y*qv.y + qv.z*qv.z + qv.w*qv.w;
    float dss = dv.x*dv.x + dv.y*dv.y + dv.z*dv.z + dv.w*dv.w;
    float qd  = qv.x*dv.x + qv.y*dv.y + qv.z*dv.z + qv.w*dv.w;
#pragma unroll
    for (int off = 32; off; off >>= 1) {
        qss += __shfl_down(qss, off);
        dss += __shfl_down(dss, off);
        qd  += __shfl_down(qd,  off);
    }
    qss = __shfl(qss, 0);
    dss = __shfl(dss, 0);
    qd  = __shfl(qd,  0);

    const float qinv = 1.0f / fmaxf(sqrtf(qss), 1e-12f);
    const float dinv = 1.0f / fmaxf(sqrtf(dss), 1e-12f);

    struct alignas(8) bf4 { __hip_bfloat16 x, y, z, w; };
    bf4 qo, doo;
    qo.x = __float2bfloat16(qv.x * qinv);
    qo.y = __float2bfloat16(qv.y * qinv);
    qo.z = __float2bfloat16(qv.z * qinv);
    qo.w = __float2bfloat16(qv.w * qinv);
    doo.x = __float2bfloat16(dv.x * dinv);
    doo.y = __float2bfloat16(dv.y * dinv);
    doo.z = __float2bfloat16(dv.z * dinv);
    doo.w = __float2bfloat16(dv.w * dinv);
    *(bf4*)(qn + (size_t)row * D_DIM + lane * 4) = qo;
    *(bf4*)(dn + (size_t)row * D_DIM + lane * 4) = doo;

    if (lane == 0) diag[row] = qd * qinv * dinv * TEMP_INV;
}

// Kernel 2: 128x128 tile of sim = qn . dn^T; fused exp(sim - 1/T) row/col sums.
// B (dn tile) staged in LDS at FULL K depth (128 rows x 256 k = 64 KB): one staging
// burst -> ONE __syncthreads per block -> zero barriers in the K-loop. A fragments
// load directly global->VGPR (16B/lane contiguous in row-major qn; L2/L3-resident),
// register-double-buffered so next-kt loads overlap this kt's MFMAs.
// B LDS XOR swizzle (row = 32 chunks of 16B): physical chunk p of row r holds logical
// (p&24)|((p&7)^(r&7)); staging keeps gld_lds' wave-uniform-base + lane*16 contiguity.
// Epilogue: butterfly all-to-all reduce -> one global atomicAdd per lane per sum.
__global__ __launch_bounds__(256) void gemm_lse_kernel(
    const __hip_bfloat16* __restrict__ qn, const __hip_bfloat16* __restrict__ dn,
    float* __restrict__ row_sums, float* __restrict__ col_sums) {
    __shared__ __hip_bfloat16 Bs[BN][D_DIM];   // 64 KB

    const int t    = threadIdx.x;
    const int lane = t & 63;
    const int w    = t >> 6;
    const int l15  = lane & 15;
    const int quad = lane >> 4;
    const int m0   = (w >> 1) * 64;
    const int n0   = (w & 1) * 64;
    const int rowBase = blockIdx.y * BM;
    const int colBase = blockIdx.x * BN;

    // --- B staging: 16 issues of 16B/thread; issue i covers rows i*8..i*8+7 ---
    const int r0 = t >> 5;               // row within an 8-row group
    const int p  = t & 31;               // physical 16B chunk within row
    const int g  = (p & 24) | ((p & 7) ^ (r0 & 7));   // global logical chunk
    const __hip_bfloat16* gb = dn + (size_t)(colBase + r0) * D_DIM + g * 8;
    __hip_bfloat16* lb = &Bs[0][0] + t * 8;
#pragma unroll
    for (int it = 0; it < 16; ++it)      // +8 rows/issue: r&7 invariant -> same swizzle
        gld_lds16(gb + (size_t)it * 8 * D_DIM, lb + it * 2048);

    // --- A kt=0 fragments: issue before the barrier (latency hidden by the drain) ---
    const __hip_bfloat16* gaBase =
        qn + (size_t)(rowBase + m0 + l15) * D_DIM + quad * 8;
    frag_ab a_cur[4], a_nxt[4];
#pragma unroll
    for (int mi = 0; mi < 4; ++mi)
        a_cur[mi] = *(const frag_ab*)(gaBase + (size_t)mi * 16 * D_DIM);

    frag_cd acc[4][4];
#pragma unroll
    for (int i = 0; i < 4; ++i)
#pragma unroll
        for (int j = 0; j < 4; ++j)
            acc[i][j] = (frag_cd){0.0f, 0.0f, 0.0f, 0.0f};

    __syncthreads();   // the ONLY barrier: drains B staging (vmcnt) + orders LDS

#pragma unroll
    for (int ks = 0; ks < 8; ++ks) {     // K = 8 x 32
        if (ks < 7) {
#pragma unroll
            for (int mi = 0; mi < 4; ++mi)
                a_nxt[mi] = *(const frag_ab*)(gaBase + (size_t)mi * 16 * D_DIM
                                              + (ks + 1) * 32);
        }
        const int c = ks * 4 + quad;     // logical 16B chunk of B rows
        frag_ab bfr[4];
#pragma unroll
        for (int i = 0; i < 4; ++i) {
            const int R  = n0 + i * 16 + l15;
            const int pc = (c & 24) | ((c & 7) ^ (l15 & 7));
            bfr[i] = *(const frag_ab*)&Bs[R][pc * 8];
        }
#pragma unroll
        for (int mi = 0; mi < 4; ++mi)
#pragma unroll
            for (int ni = 0; ni < 4; ++ni)
                acc[mi][ni] = __builtin_amdgcn_mfma_f32_16x16x32_bf16(
                    a_cur[mi], bfr[ni], acc[mi][ni], 0, 0, 0);
        if (ks < 7) {
#pragma unroll
            for (int mi = 0; mi < 4; ++mi) a_cur[mi] = a_nxt[mi];
        }
    }

    // ---- Epilogue ----
    // C frag layout (m89): lane holds col = n0+ni*16+l15, row = m0+mi*16+quad*4+r.
    float rv[16];
    float cv[4] = {0.0f, 0.0f, 0.0f, 0.0f};
#pragma unroll
    for (int pp = 0; pp < 16; ++pp) rv[pp] = 0.0f;
#pragma unroll
    for (int mi = 0; mi < 4; ++mi)
#pragma unroll
        for (int ni = 0; ni < 4; ++ni)
#pragma unroll
            for (int r = 0; r < 4; ++r) {
                const float e = __expf((acc[mi][ni][r] - 1.0f) * TEMP_INV);
                rv[mi * 4 + r] += e;
                cv[ni] += e;
            }

    // Row butterfly all-reduce over the 16 lanes of each quad; end: rv[0] <-> p = l15.
#pragma unroll
    for (int s = 0; s < 4; ++s) {
        const bool b = (l15 >> s) & 1;
#pragma unroll
        for (int i = 0; i < (8 >> s); ++i) {
            const float a0 = rv[2 * i], a1 = rv[2 * i + 1];
            const float keep = b ? a1 : a0;
            const float send = b ? a0 : a1;
            rv[i] = keep + __shfl_xor(send, 1 << s);
        }
    }
    atomicAdd(&row_sums[rowBase + m0 + (l15 >> 2) * 16 + quad * 4 + (l15 & 3)], rv[0]);

    // Col butterfly all-reduce over the 4 quads; end: cv[0] <-> ni = quad.
#pragma unroll
    for (int s = 0; s < 2; ++s) {
        const bool b = (quad >> s) & 1;
#pragma unroll
        for (int i = 0; i < (2 >> s); ++i) {
            const float a0 = cv[2 * i], a1 = cv[2 * i + 1];
            const float keep = b ? a1 : a0;
            const float send = b ? a0 : a1;
            cv[i] = keep + __shfl_xor(send, 16 << s);
        }
    }
    atomicAdd(&col_sums[colBase + n0 + quad * 16 + l15], cv[0]);
}

// Kernel 3 (parallel): each block reduces 256 rows, atomicAdd into zeroed out[0].
__global__ __launch_bounds__(256) void finalize_kernel(
    const float* __restrict__ rs, const float* __restrict__ cs,
    const float* __restrict__ dg, float* __restrict__ out) {
    const int i = blockIdx.x * 256 + threadIdx.x;
    float s = logf(rs[i]) + logf(cs[i]) - 2.0f * dg[i];
#pragma unroll
    for (int off = 32; off; off >>= 1) s += __shfl_down(s, off);
    __shared__ float buf[4];
    if ((threadIdx.x & 63) == 0) buf[threadIdx.x >> 6] = s;
    __syncthreads();
    if (threadIdx.x == 0) {
        float tot = (buf[0] + buf[1] + buf[2] + buf[3]) / (2.0f * B_ROWS);
        if (blockIdx.x == 0) tot += TEMP_INV;   // undo the fixed exp shift
        atomicAdd(out, tot);
    }
}

extern "C" void kernel_launch(void* const* d_in, const int* in_sizes, int n_in,
                              void* d_out, int out_size, void* d_ws, size_t ws_size,
                              hipStream_t stream) {
    const float* q = (const float*)d_in[0];
    const float* d = (const float*)d_in[1];
    float* out = (float*)d_out;

    char* ws = (char*)d_ws;
    __hip_bfloat16* qn = (__hip_bfloat16*)ws;                       // 8 MB
    __hip_bfloat16* dn = qn + (size_t)B_ROWS * D_DIM;               // 8 MB
    float* row_sums = (float*)(ws + 2 * (size_t)B_ROWS * D_DIM * sizeof(__hip_bfloat16));
    float* col_sums = row_sums + B_ROWS;
    float* diag     = col_sums + B_ROWS;

    norm_diag_kernel<<<B_ROWS / 4, 256, 0, stream>>>(q, d, qn, dn, diag,
                                                     row_sums, col_sums, out);
    gemm_lse_kernel<<<dim3(B_ROWS / BN, B_ROWS / BM), 256, 0, stream>>>(qn, dn, row_sums, col_sums);
    finalize_kernel<<<B_ROWS / 256, 256, 0, stream>>>(row_sums, col_sums, diag, out);
}

// Round 6
// 266.491 us; speedup vs baseline: 1.4240x; 1.4240x over previous
//
#include <hip/hip_runtime.h>
#include <hip/hip_bf16.h>
#include <cstdint>
#include <cstddef>

#define B_ROWS 16384
#define D_DIM  256
#define TEMP_INV 14.285714285714286f   // 1/0.07

#define BM 128
#define BN 128
#define BK 64

using frag_ab = __attribute__((ext_vector_type(8))) short;   // 8 bf16
using frag_cd = __attribute__((ext_vector_type(4))) float;   // 4 fp32

__device__ __forceinline__ void gld_lds16(const void* g, void* l) {
    __builtin_amdgcn_global_load_lds(
        (const __attribute__((address_space(1))) void*)g,
        (__attribute__((address_space(3))) void*)l,
        16, 0, 0);
}

// Kernel 1: L2-normalize q,d rows -> bf16; diag[i] = cos(q_i,d_i)/T in fp32.
// Also zero-initializes row_sums/col_sums/out (replaces memset dispatches).
__global__ __launch_bounds__(256) void norm_diag_kernel(
    const float* __restrict__ q, const float* __restrict__ d,
    __hip_bfloat16* __restrict__ qn, __hip_bfloat16* __restrict__ dn,
    float* __restrict__ diag,
    float* __restrict__ row_sums, float* __restrict__ col_sums,
    float* __restrict__ out) {
    const int b = blockIdx.x;
    if (b < 64)            row_sums[b * 256 + threadIdx.x] = 0.0f;
    else if (b < 128)      col_sums[(b - 64) * 256 + threadIdx.x] = 0.0f;
    else if (b == 128 && threadIdx.x == 0) out[0] = 0.0f;

    const int row  = b * 4 + (threadIdx.x >> 6);
    const int lane = threadIdx.x & 63;

    const float4 qv = ((const float4*)(q + (size_t)row * D_DIM))[lane];
    const float4 dv = ((const float4*)(d + (size_t)row * D_DIM))[lane];

    float qss = qv.x*qv.x + qv.y*qv.y + qv.z*qv.z + qv.w*qv.w;
    float dss = dv.x*dv.x + dv.y*dv.y + dv.z*dv.z + dv.w*dv.w;
    float qd  = qv.x*dv.x + qv.y*dv.y + qv.z*dv.z + qv.w*dv.w;
#pragma unroll
    for (int off = 32; off; off >>= 1) {
        qss += __shfl_down(qss, off);
        dss += __shfl_down(dss, off);
        qd  += __shfl_down(qd,  off);
    }
    qss = __shfl(qss, 0);
    dss = __shfl(dss, 0);
    qd  = __shfl(qd,  0);

    const float qinv = 1.0f / fmaxf(sqrtf(qss), 1e-12f);
    const float dinv = 1.0f / fmaxf(sqrtf(dss), 1e-12f);

    struct alignas(8) bf4 { __hip_bfloat16 x, y, z, w; };
    bf4 qo, doo;
    qo.x = __float2bfloat16(qv.x * qinv);
    qo.y = __float2bfloat16(qv.y * qinv);
    qo.z = __float2bfloat16(qv.z * qinv);
    qo.w = __float2bfloat16(qv.w * qinv);
    doo.x = __float2bfloat16(dv.x * dinv);
    doo.y = __float2bfloat16(dv.y * dinv);
    doo.z = __float2bfloat16(dv.z * dinv);
    doo.w = __float2bfloat16(dv.w * dinv);
    *(bf4*)(qn + (size_t)row * D_DIM + lane * 4) = qo;
    *(bf4*)(dn + (size_t)row * D_DIM + lane * 4) = doo;

    if (lane == 0) diag[row] = qd * qinv * dinv * TEMP_INV;
}

// Kernel 2: 128x128 tile of sim = qn . dn^T; fused exp(sim - 1/T) row/col sums.
// R4 core (measured best: ~205 us, 0 bank conflicts): BK=64, XOR-swizzled LDS
// (conflict-free ONLY at 128B row stride — R3/R5 showed wider rows pay 4 cyc/read),
// gld_lds width-16 staging, butterfly all-to-all epilogue reduce.
// NEW: XCD-aware block swizzle. 1D grid; xcd = id&7 owns a 16-column stripe
// (bx = xcd*16 + (j&15), by = j>>7 via j=id>>3). Per-XCD hot set: 16 dn bands
// (1 MB) + ~4 qn bands (256 KB) -> resident in the XCD's 4 MB L2, so staging
// drains hit L2 (~200 cyc) instead of LLC/HBM (~600-900 cyc).
__global__ __launch_bounds__(256) void gemm_lse_kernel(
    const __hip_bfloat16* __restrict__ qn, const __hip_bfloat16* __restrict__ dn,
    float* __restrict__ row_sums, float* __restrict__ col_sums) {
    __shared__ __hip_bfloat16 As[BM][BK];   // 16 KB
    __shared__ __hip_bfloat16 Bs[BN][BK];   // 16 KB

    const int t    = threadIdx.x;
    const int lane = t & 63;
    const int w    = t >> 6;
    const int l15  = lane & 15;
    const int quad = lane >> 4;
    const int m0   = (w >> 1) * 64;
    const int n0   = (w & 1) * 64;

    // XCD swizzle: id -> (bx, by)
    const int id  = blockIdx.x;
    const int xcd = id & 7;
    const int j   = id >> 3;
    const int bx  = (xcd << 4) | (j & 15);
    const int by  = j >> 4;
    const int rowBase = by * BM;
    const int colBase = bx * BN;

    // staging map: thread t -> row t/8, GLOBAL k-chunk ((t&7)^(row&7)); LDS offset = t*16B
    const int rsub = t >> 3;
    const int ksub = (((t & 7) ^ (rsub & 7)) << 3);
    const __hip_bfloat16* ga = qn + (size_t)(rowBase + rsub) * D_DIM + ksub;
    const __hip_bfloat16* gb = dn + (size_t)(colBase + rsub) * D_DIM + ksub;
    __hip_bfloat16* la = &As[0][0] + t * 8;   // physical slot, unswizzled
    __hip_bfloat16* lb = &Bs[0][0] + t * 8;

    frag_cd acc[4][4];
#pragma unroll
    for (int i = 0; i < 4; ++i)
#pragma unroll
        for (int jj = 0; jj < 4; ++jj)
            acc[i][jj] = (frag_cd){0.0f, 0.0f, 0.0f, 0.0f};

    for (int kt = 0; kt < D_DIM; kt += BK) {
        if (kt) __syncthreads();
#pragma unroll
        for (int it = 0; it < 4; ++it) {   // +32 rows: (row&7) invariant, same swizzle
            gld_lds16(ga + (size_t)it * 32 * D_DIM + kt, la + it * 32 * BK);
            gld_lds16(gb + (size_t)it * 32 * D_DIM + kt, lb + it * 32 * BK);
        }
        __syncthreads();   // drains vmcnt (global_load_lds) + orders LDS

#pragma unroll
        for (int kk = 0; kk < BK; kk += 32) {
            const int c = (kk >> 3) + quad;          // logical 16B-chunk index
            frag_ab af[4], bfr[4];
#pragma unroll
            for (int i = 0; i < 4; ++i) {
                const int R = m0 + i * 16 + l15;
                af[i]  = *(const frag_ab*)&As[R][(c ^ (l15 & 7)) << 3];
            }
#pragma unroll
            for (int i = 0; i < 4; ++i) {
                const int R = n0 + i * 16 + l15;
                bfr[i] = *(const frag_ab*)&Bs[R][(c ^ (l15 & 7)) << 3];
            }
#pragma unroll
            for (int mi = 0; mi < 4; ++mi)
#pragma unroll
                for (int ni = 0; ni < 4; ++ni)
                    acc[mi][ni] = __builtin_amdgcn_mfma_f32_16x16x32_bf16(
                        af[mi], bfr[ni], acc[mi][ni], 0, 0, 0);
        }
    }

    // ---- Epilogue ----
    // C frag layout (m89): lane holds col = n0+ni*16+l15, row = m0+mi*16+quad*4+r.
    float rv[16];
    float cv[4] = {0.0f, 0.0f, 0.0f, 0.0f};
#pragma unroll
    for (int pp = 0; pp < 16; ++pp) rv[pp] = 0.0f;
#pragma unroll
    for (int mi = 0; mi < 4; ++mi)
#pragma unroll
        for (int ni = 0; ni < 4; ++ni)
#pragma unroll
            for (int r = 0; r < 4; ++r) {
                const float e = __expf((acc[mi][ni][r] - 1.0f) * TEMP_INV);
                rv[mi * 4 + r] += e;
                cv[ni] += e;
            }

    // Row butterfly all-reduce over the 16 lanes of each quad; end: rv[0] <-> p = l15.
#pragma unroll
    for (int s = 0; s < 4; ++s) {
        const bool b = (l15 >> s) & 1;
#pragma unroll
        for (int i = 0; i < (8 >> s); ++i) {
            const float a0 = rv[2 * i], a1 = rv[2 * i + 1];
            const float keep = b ? a1 : a0;
            const float send = b ? a0 : a1;
            rv[i] = keep + __shfl_xor(send, 1 << s);
        }
    }
    atomicAdd(&row_sums[rowBase + m0 + (l15 >> 2) * 16 + quad * 4 + (l15 & 3)], rv[0]);

    // Col butterfly all-reduce over the 4 quads; end: cv[0] <-> ni = quad.
#pragma unroll
    for (int s = 0; s < 2; ++s) {
        const bool b = (quad >> s) & 1;
#pragma unroll
        for (int i = 0; i < (2 >> s); ++i) {
            const float a0 = cv[2 * i], a1 = cv[2 * i + 1];
            const float keep = b ? a1 : a0;
            const float send = b ? a0 : a1;
            cv[i] = keep + __shfl_xor(send, 16 << s);
        }
    }
    atomicAdd(&col_sums[colBase + n0 + quad * 16 + l15], cv[0]);
}

// Kernel 3 (parallel): each block reduces 256 rows, atomicAdd into zeroed out[0].
__global__ __launch_bounds__(256) void finalize_kernel(
    const float* __restrict__ rs, const float* __restrict__ cs,
    const float* __restrict__ dg, float* __restrict__ out) {
    const int i = blockIdx.x * 256 + threadIdx.x;
    float s = logf(rs[i]) + logf(cs[i]) - 2.0f * dg[i];
#pragma unroll
    for (int off = 32; off; off >>= 1) s += __shfl_down(s, off);
    __shared__ float buf[4];
    if ((threadIdx.x & 63) == 0) buf[threadIdx.x >> 6] = s;
    __syncthreads();
    if (threadIdx.x == 0) {
        float tot = (buf[0] + buf[1] + buf[2] + buf[3]) / (2.0f * B_ROWS);
        if (blockIdx.x == 0) tot += TEMP_INV;   // undo the fixed exp shift
        atomicAdd(out, tot);
    }
}

extern "C" void kernel_launch(void* const* d_in, const int* in_sizes, int n_in,
                              void* d_out, int out_size, void* d_ws, size_t ws_size,
                              hipStream_t stream) {
    const float* q = (const float*)d_in[0];
    const float* d = (const float*)d_in[1];
    float* out = (float*)d_out;

    char* ws = (char*)d_ws;
    __hip_bfloat16* qn = (__hip_bfloat16*)ws;                       // 8 MB
    __hip_bfloat16* dn = qn + (size_t)B_ROWS * D_DIM;               // 8 MB
    float* row_sums = (float*)(ws + 2 * (size_t)B_ROWS * D_DIM * sizeof(__hip_bfloat16));
    float* col_sums = row_sums + B_ROWS;
    float* diag     = col_sums + B_ROWS;

    norm_diag_kernel<<<B_ROWS / 4, 256, 0, stream>>>(q, d, qn, dn, diag,
                                                     row_sums, col_sums, out);
    gemm_lse_kernel<<<(B_ROWS / BM) * (B_ROWS / BN), 256, 0, stream>>>(qn, dn, row_sums, col_sums);
    finalize_kernel<<<B_ROWS / 256, 256, 0, stream>>>(row_sums, col_sums, diag, out);
}